// Round 6
// baseline (391.237 us; speedup 1.0000x reference)
//
#include <hip/hip_runtime.h>

#define E_EDGES 1000000
#define NNODES  100000
#define HID     128
#define NGROUPS 15625      // 64-edge groups, exact
#define NSTREAM 1024       // 256 blocks x 4 waves, one independent stream each

typedef float f32x4 __attribute__((ext_vector_type(4)));
typedef short s16x8 __attribute__((ext_vector_type(8)));

// float -> bf16, round-to-nearest-even (inputs are finite)
__device__ __forceinline__ unsigned short f2bf(float f) {
  unsigned int u = __float_as_uint(f);
  u += 0x7FFFu + ((u >> 16) & 1u);
  return (unsigned short)(u >> 16);
}

__device__ __forceinline__ int4 pack8(float4 a, float4 b) {
  int4 v;
  v.x = (int)((unsigned)f2bf(a.x) | ((unsigned)f2bf(a.y) << 16));
  v.y = (int)((unsigned)f2bf(a.z) | ((unsigned)f2bf(a.w) << 16));
  v.z = (int)((unsigned)f2bf(b.x) | ((unsigned)f2bf(b.y) << 16));
  v.w = (int)((unsigned)f2bf(b.z) | ((unsigned)f2bf(b.w) << 16));
  return v;
}

__global__ void cast_x_kernel(const float* __restrict__ x,
                              unsigned short* __restrict__ xb) {
  int i = blockIdx.x * blockDim.x + threadIdx.x;
  const float4* p = (const float4*)x;
  float4 a = p[2 * i];
  float4 b = p[2 * i + 1];
  int4 v = pack8(a, b);
  ((int4*)xb)[i] = v;
}

// Correct-but-slow insurance path if workspace is too small for bf16 x.
__global__ void edge_naive(const float* __restrict__ x, const int* __restrict__ ei,
                           const float* __restrict__ attr, const float* __restrict__ W1,
                           const float* __restrict__ b1, const float* __restrict__ W2,
                           const float* __restrict__ b2, const float* __restrict__ W3,
                           const float* __restrict__ b3, float* __restrict__ out) {
  const int e = blockIdx.x * blockDim.x + threadIdx.x;
  if (e >= E_EDGES) return;
  const float* xs = x + (size_t)ei[e] * HID;
  const float* xd = x + (size_t)ei[E_EDGES + e] * HID;
  const float a = attr[e];
  float h1[HID];
  for (int n = 0; n < HID; ++n) {
    float s = b1[n] + a * W1[256 * HID + n];
    for (int k = 0; k < HID; ++k)
      s += xs[k] * W1[k * HID + n] + xd[k] * W1[(128 + k) * HID + n];
    h1[n] = fmaxf(s, 0.f);
  }
  float o = b3[0];
  for (int n2 = 0; n2 < 32; ++n2) {
    float s = b2[n2];
    for (int n = 0; n < HID; ++n) s += h1[n] * W2[n * 32 + n2];
    o += fmaxf(s, 0.f) * W3[n2];
  }
  out[e] = 1.f / (1.f + __expf(-o));
}

// 256 threads = 4 waves; each wave is an INDEPENDENT stream of 64-edge groups
// (wave ws handles groups ws, ws+1024, ...). No __syncthreads in the main loop:
// W1 sits read-only in LDS (one init barrier), A-fragments come straight from
// global memory into VGPRs (lane=edge-row, quad=k-chunk -> 16 rows x 64B
// contiguous per load instr), h1 round-trips through a wave-PRIVATE padded LDS
// region ordered by in-wave lgkmcnt only. acc double-buffered in AGPRs so the
// epilogue+L2 of group g-1 interleaves into the MFMA k-loop of group g.
__launch_bounds__(256, 1)
__global__ void edge_mlp_kernel(const unsigned short* __restrict__ xb,
                                const int* __restrict__ ei,
                                const float* __restrict__ attr,
                                const float* __restrict__ W1,
                                const float* __restrict__ b1,
                                const float* __restrict__ W2,
                                const float* __restrict__ b2,
                                const float* __restrict__ W3,
                                const float* __restrict__ b3,
                                float* __restrict__ out) {
  // B-frag bank: frag(ks,ct) = 1KB, lane(q,l15) holds W1[k=ks*32+q*8+j][n=ct*16+l15]
  __shared__ __align__(16) unsigned char W1L[65536];
  // h1: per-wave 64 rows x 272B (16B pad/row -> rows shift banks by 4; 2-way max)
  __shared__ __align__(16) unsigned char h1L[4 * 64 * 272];   // 68 KB

  const int tid  = threadIdx.x;
  const int w    = tid >> 6;
  const int lane = tid & 63;
  const int q    = lane >> 4;
  const int l15  = lane & 15;
  const int hbase = w * (64 * 272);

  // ---- fill W1L: wave w fills k-steps 2w, 2w+1 ... (8 total) ----
#pragma unroll
  for (int kk = 0; kk < 2; ++kk) {
    const int ks = w * 2 + kk;
#pragma unroll
    for (int ct = 0; ct < 8; ++ct) {
      s16x8 f;
#pragma unroll
      for (int j = 0; j < 8; ++j)
        f[j] = (short)f2bf(W1[(ks * 32 + q * 8 + j) * HID + ct * 16 + l15]);
      *(s16x8*)&W1L[((ks * 8 + ct) << 10) + lane * 16] = f;
    }
  }

  // ---- per-lane epilogue weights ----
  float b1v[8], w1l[8];
#pragma unroll
  for (int ct = 0; ct < 8; ++ct) {
    b1v[ct] = b1[ct * 16 + l15];
    w1l[ct] = W1[256 * HID + ct * 16 + l15];   // attr column (k=256)
  }
  // L2 weights, k PERMUTED to match h1 packing: position p=(l15w*8+ct) holds
  // col n=ct*16+l15w  =>  n(p) = (p&7)*16 + (p>>3)
  s16x8 B2[2][4];
#pragma unroll
  for (int nt = 0; nt < 2; ++nt)
#pragma unroll
    for (int s2 = 0; s2 < 4; ++s2)
#pragma unroll
      for (int j = 0; j < 8; ++j) {
        const int n = j * 16 + s2 * 4 + q;
        B2[nt][s2][j] = (short)f2bf(W2[n * 32 + nt * 16 + l15]);
      }
  const float b2v0 = b2[l15],      w3v0 = W3[l15];
  const float b2v1 = b2[16 + l15], w3v1 = W3[16 + l15];
  const float b3v  = b3[0];

  __syncthreads();   // W1L ready; the ONLY block-wide barrier

  const int ws  = blockIdx.x * 4 + w;                  // stream id
  const int ngr = (NGROUPS - ws + NSTREAM - 1) / NSTREAM;

  f32x4 accN[4][8], accP[4][8];   // 2 x 128 AGPR accumulator banks
  int nidC[8], nidN[8];
  f32x4 attrv[4];

  // prologue: edge ids for first group (sd = i>>2, mt = i&3)
  {
    const int base = ws * 64;
#pragma unroll
    for (int i = 0; i < 8; ++i)
      nidC[i] = ei[(i >> 2) * E_EDGES + base + (i & 3) * 16 + l15];
  }

  for (int it = 0; it <= ngr; ++it) {
    const int g    = ws + it * NSTREAM;
    const int gp   = g - NSTREAM;         // epilogue group
    const bool doL1  = (it < ngr);
    const bool doEpi = (it > 0);

    // attr for the epilogue group (consumed after ~2 k-steps)
    if (doEpi) {
#pragma unroll
      for (int mt = 0; mt < 4; ++mt)
        attrv[mt] = *(const f32x4*)(attr + gp * 64 + mt * 16 + q * 4);
    }
    // edge ids one group ahead
    if (it + 1 < ngr) {
      const int base1 = (g + NSTREAM) * 64;
#pragma unroll
      for (int i = 0; i < 8; ++i)
        nidN[i] = ei[(i >> 2) * E_EDGES + base1 + (i & 3) * 16 + l15];
    }

    // epilogue chunk for (gp, mt): h1 pack/write -> A2 -> L2 MFMA -> sigmoid -> out
    auto epi_chunk = [&](int mt) {
#pragma unroll
      for (int r = 0; r < 4; ++r) {
        const int row = mt * 16 + q * 4 + r;
        s16x8 pk;
#pragma unroll
        for (int ct = 0; ct < 8; ++ct) {
          float v = accP[mt][ct][r] + b1v[ct] + attrv[mt][r] * w1l[ct];
          pk[ct] = (short)f2bf(fmaxf(v, 0.f));
        }
        const int ch = l15 ^ ((row >> 1) & 7);
        *(s16x8*)&h1L[hbase + row * 272 + ch * 16] = pk;
      }
      f32x4 c0 = {0.f, 0.f, 0.f, 0.f}, c1 = {0.f, 0.f, 0.f, 0.f};
#pragma unroll
      for (int s2 = 0; s2 < 4; ++s2) {
        const int row = mt * 16 + l15;
        const int ch  = (s2 * 4 + q) ^ ((l15 >> 1) & 7);
        const s16x8 A2 = *(const s16x8*)&h1L[hbase + row * 272 + ch * 16];
        c0 = __builtin_amdgcn_mfma_f32_16x16x32_bf16(A2, B2[0][s2], c0, 0, 0, 0);
        c1 = __builtin_amdgcn_mfma_f32_16x16x32_bf16(A2, B2[1][s2], c1, 0, 0, 0);
      }
      float p[4];
#pragma unroll
      for (int r = 0; r < 4; ++r)
        p[r] = fmaxf(c0[r] + b2v0, 0.f) * w3v0 + fmaxf(c1[r] + b2v1, 0.f) * w3v1;
#pragma unroll
      for (int off = 8; off >= 1; off >>= 1)
#pragma unroll
        for (int r = 0; r < 4; ++r)
          p[r] += __shfl_xor(p[r], off, 16);
      if (l15 == 0) {
        float4 o;
#pragma unroll
        for (int r = 0; r < 4; ++r)
          ((float*)&o)[r] = 1.f / (1.f + __expf(-(p[r] + b3v)));
        *(float4*)(out + gp * 64 + mt * 16 + q * 4) = o;
      }
    };

    if (doL1) {
#pragma unroll
      for (int mt = 0; mt < 4; ++mt)
#pragma unroll
        for (int ct = 0; ct < 8; ++ct)
          accN[mt][ct] = (f32x4){0.f, 0.f, 0.f, 0.f};

      s16x8 Af[2][4];
      // A prologue (ks=0, side 0): lane(q,l15) = edge row l15, k-bytes q*16..
#pragma unroll
      for (int mt = 0; mt < 4; ++mt)
        Af[0][mt] = *(const s16x8*)(xb + (size_t)nidC[mt] * HID + q * 8);

#pragma unroll
      for (int ks = 0; ks < 8; ++ks) {
        const int pb = ks & 1;
        if (ks < 7) {
          const int kn = ks + 1, sdn = kn >> 2, kcn = kn & 3;
#pragma unroll
          for (int mt = 0; mt < 4; ++mt)
            Af[pb ^ 1][mt] = *(const s16x8*)
                (xb + (size_t)nidC[sdn * 4 + mt] * HID + kcn * 32 + q * 8);
        }
#pragma unroll
        for (int h = 0; h < 2; ++h) {
          s16x8 Bf[4];
#pragma unroll
          for (int c4 = 0; c4 < 4; ++c4)
            Bf[c4] = *(const s16x8*)&W1L[((ks * 8 + h * 4 + c4) << 10) + lane * 16];
#pragma unroll
          for (int mt = 0; mt < 4; ++mt)
#pragma unroll
            for (int c4 = 0; c4 < 4; ++c4)
              accN[mt][h * 4 + c4] = __builtin_amdgcn_mfma_f32_16x16x32_bf16(
                  Af[pb][mt], Bf[c4], accN[mt][h * 4 + c4], 0, 0, 0);
        }
        if (doEpi && (ks & 1)) epi_chunk(ks >> 1);   // interleave prev-group epilogue
      }
    } else if (doEpi) {
#pragma unroll
      for (int mt = 0; mt < 4; ++mt) epi_chunk(mt);
    }

    // rotate pipeline state
    if (doL1) {
#pragma unroll
      for (int mt = 0; mt < 4; ++mt)
#pragma unroll
        for (int ct = 0; ct < 8; ++ct)
          accP[mt][ct] = accN[mt][ct];
#pragma unroll
      for (int i = 0; i < 8; ++i) nidC[i] = nidN[i];
    }
  }
}

extern "C" void kernel_launch(void* const* d_in, const int* in_sizes, int n_in,
                              void* d_out, int out_size, void* d_ws, size_t ws_size,
                              hipStream_t stream) {
  const float* x    = (const float*)d_in[0];
  const int*   ei   = (const int*)d_in[1];
  const float* attr = (const float*)d_in[2];
  const float* W1   = (const float*)d_in[3];
  const float* b1   = (const float*)d_in[4];
  const float* W2   = (const float*)d_in[5];
  const float* b2   = (const float*)d_in[6];
  const float* W3   = (const float*)d_in[7];
  const float* b3   = (const float*)d_in[8];
  float* out = (float*)d_out;

  const size_t need = (size_t)NNODES * HID * sizeof(unsigned short);  // 25.6 MB
  if (ws_size >= need) {
    unsigned short* xb = (unsigned short*)d_ws;
    cast_x_kernel<<<6250, 256, 0, stream>>>(x, xb);
    edge_mlp_kernel<<<256, 256, 0, stream>>>(xb, ei, attr, W1, b1, W2, b2, W3, b3, out);
  } else {
    edge_naive<<<(E_EDGES + 255) / 256, 256, 0, stream>>>(x, ei, attr, W1, b1, W2, b2, W3, b3, out);
  }
}

// Round 7
// 233.660 us; speedup vs baseline: 1.6744x; 1.6744x over previous
//
#include <hip/hip_runtime.h>

#define E_EDGES 1000000
#define NNODES  100000
#define HID     128
#define NG      31250     // 32-edge groups, exact
#define NBLK    768       // 3 blocks/CU x 256 CUs

typedef float f32x4 __attribute__((ext_vector_type(4)));
typedef short s16x8 __attribute__((ext_vector_type(8)));

typedef __attribute__((address_space(3))) unsigned int lds_u32;
typedef const __attribute__((address_space(1))) unsigned int glb_u32;

// async 16B/lane global->LDS: per-lane global addr, wave-uniform LDS base +
// lane*16 deposit. Completion enforced by the compiler's vmcnt(0) drain at
// s_barrier (one barrier later than issue -> latency hidden by compute).
__device__ __forceinline__ void gl_lds16(const void* g, void* l) {
  __builtin_amdgcn_global_load_lds((glb_u32*)g, (lds_u32*)l, 16, 0, 0);
}

// float -> bf16, round-to-nearest-even (inputs are finite)
__device__ __forceinline__ unsigned short f2bf(float f) {
  unsigned int u = __float_as_uint(f);
  u += 0x7FFFu + ((u >> 16) & 1u);
  return (unsigned short)(u >> 16);
}

__device__ __forceinline__ int4 pack8(float4 a, float4 b) {
  int4 v;
  v.x = (int)((unsigned)f2bf(a.x) | ((unsigned)f2bf(a.y) << 16));
  v.y = (int)((unsigned)f2bf(a.z) | ((unsigned)f2bf(a.w) << 16));
  v.z = (int)((unsigned)f2bf(b.x) | ((unsigned)f2bf(b.y) << 16));
  v.w = (int)((unsigned)f2bf(b.z) | ((unsigned)f2bf(b.w) << 16));
  return v;
}

__global__ void cast_x_kernel(const float* __restrict__ x,
                              unsigned short* __restrict__ xb) {
  int i = blockIdx.x * blockDim.x + threadIdx.x;
  const float4* p = (const float4*)x;
  float4 a = p[2 * i];
  float4 b = p[2 * i + 1];
  int4 v = pack8(a, b);
  ((int4*)xb)[i] = v;
}

// Correct-but-slow insurance path if workspace is too small for bf16 x.
__global__ void edge_naive(const float* __restrict__ x, const int* __restrict__ ei,
                           const float* __restrict__ attr, const float* __restrict__ W1,
                           const float* __restrict__ b1, const float* __restrict__ W2,
                           const float* __restrict__ b2, const float* __restrict__ W3,
                           const float* __restrict__ b3, float* __restrict__ out) {
  const int e = blockIdx.x * blockDim.x + threadIdx.x;
  if (e >= E_EDGES) return;
  const float* xs = x + (size_t)ei[e] * HID;
  const float* xd = x + (size_t)ei[E_EDGES + e] * HID;
  const float a = attr[e];
  float h1[HID];
  for (int n = 0; n < HID; ++n) {
    float s = b1[n] + a * W1[256 * HID + n];
    for (int k = 0; k < HID; ++k)
      s += xs[k] * W1[k * HID + n] + xd[k] * W1[(128 + k) * HID + n];
    h1[n] = fmaxf(s, 0.f);
  }
  float o = b3[0];
  for (int n2 = 0; n2 < 32; ++n2) {
    float s = b2[n2];
    for (int n = 0; n < HID; ++n) s += h1[n] * W2[n * 32 + n2];
    o += fmaxf(s, 0.f) * W3[n2];
  }
  out[e] = 1.f / (1.f + __expf(-o));
}

// 256 threads = 4 waves; 32-edge groups (2 M-tiles); grid-stride by NBLK.
// Depth-3 pipeline, ONE barrier per group:
//   epoch(it): DMA(g+1 -> ef[p^1]) | nid(g+2) | L1(g: ef[p]->h1[p]) |
//              L2(g-1: h1[p^1]->red[p]) | out(g-2: red[p^1]) | barrier
// ef layout: [side sd][row m][slot]16B, slot holds global k-chunk slot^(m&7)
//   (XOR applied on the GLOBAL address so the DMA's linear lane*16 deposit
//    lands swizzled; A-reads then vary row across lanes conflict-benignly).
// h1 layout: per tile 16 rows x 272B (256B data + 16B pad -> 16B-chunk column
//   advances +1 per row: b128 A2 reads are 2-way max = free). Row data is
//   k-PERMUTED: dword d = w*16+l15 holds cols (w*32+l15, w*32+16+l15) so the
//   L1 epilogue packs 2 bf16 -> one u32 write; B2 is built with the same
//   permutation (dot products are order-invariant).
__launch_bounds__(256, 3)
__global__ void edge_mlp_kernel(const unsigned short* __restrict__ xb,
                                const int* __restrict__ ei,
                                const float* __restrict__ attr,
                                const float* __restrict__ W1,
                                const float* __restrict__ b1,
                                const float* __restrict__ W2,
                                const float* __restrict__ b2,
                                const float* __restrict__ W3,
                                const float* __restrict__ b3,
                                float* __restrict__ out) {
  __shared__ __align__(16) unsigned char ef[2][16384];   // 32 KB
  __shared__ __align__(16) unsigned char h1b[2][8704];   // 17 KB
  __shared__ float red[2][4][16];                        // 512 B

  const int tid  = threadIdx.x;
  const int w    = tid >> 6;
  const int lane = tid & 63;
  const int q    = lane >> 4;
  const int l15  = lane & 15;

  // ---- L1 weights: wave w owns output cols w*32 .. w*32+31 (2 col-tiles) ----
  s16x8 B1[2][8];
  float b1v[2], w1l[2];
#pragma unroll
  for (int th = 0; th < 2; ++th) {
    const int nc = w * 32 + th * 16 + l15;
#pragma unroll
    for (int s = 0; s < 8; ++s)
#pragma unroll
      for (int j = 0; j < 8; ++j)
        B1[th][s][j] = (short)f2bf(W1[(s * 32 + q * 8 + j) * HID + nc]);
    b1v[th] = b1[nc];
    w1l[th] = W1[256 * HID + nc];   // attr column (k=256)
  }
  // ---- L2 weights: wave w -> tile w>>1, half w&1; k in h1 storage order ----
  const int n2 = (w & 1) * 16 + l15;
  s16x8 B2[4];
#pragma unroll
  for (int s2 = 0; s2 < 4; ++s2)
#pragma unroll
    for (int j = 0; j < 8; ++j) {
      const int e = s2 * 32 + q * 8 + j;                       // storage index
      const int n = (e >> 5) * 32 + (e & 1) * 16 + ((e >> 1) & 15);
      B2[s2][j] = (short)f2bf(W2[n * 32 + n2]);
    }
  const float b2v = b2[n2];
  const float w3v = W3[n2];
  const float b3v = b3[0];

  const int bx = blockIdx.x;
  int nidA[4] = {0, 0, 0, 0}, nidB[4] = {0, 0, 0, 0};
  const int itmax = (NG - 1 - bx) / NBLK + 2;

  // ---- prologue: ids(g0) -> DMA(g0 -> ef[0]); ids(g1) -> nidB ----
  {
#pragma unroll
    for (int i = 0; i < 4; ++i) {
      const int f = w * 4 + i;
      nidA[i] = ei[(f >> 3) * E_EDGES + bx * 32 + (f & 7) * 4 + q];
    }
#pragma unroll
    for (int i = 0; i < 4; ++i) {
      const int f = w * 4 + i, m = (f & 7) * 4 + q;
      gl_lds16(xb + (size_t)nidA[i] * HID + ((l15 ^ (m & 7)) << 3),
               &ef[0][f * 1024]);
    }
    const int g1 = bx + NBLK;
    if (g1 < NG) {
#pragma unroll
      for (int i = 0; i < 4; ++i) {
        const int f = w * 4 + i;
        nidB[i] = ei[(f >> 3) * E_EDGES + g1 * 32 + (f & 7) * 4 + q];
      }
    }
  }
  __syncthreads();   // drains DMA(g0)

#define ITER(IT, P, NIDU, NIDL)                                               \
  {                                                                           \
    const int g   = bx + (IT) * NBLK;                                         \
    const int g1  = g + NBLK;                                                 \
    const int g2  = g + 2 * NBLK;                                             \
    const int gm1 = g - NBLK;                                                 \
    const int gm2 = g - 2 * NBLK;                                             \
    if (g1 < NG) {                                                            \
      _Pragma("unroll") for (int i = 0; i < 4; ++i) {                         \
        const int f = w * 4 + i, m = (f & 7) * 4 + q;                         \
        gl_lds16(xb + (size_t)NIDU[i] * HID + ((l15 ^ (m & 7)) << 3),         \
                 &ef[(P) ^ 1][f * 1024]);                                     \
      }                                                                       \
    }                                                                         \
    if (g2 < NG) {                                                            \
      _Pragma("unroll") for (int i = 0; i < 4; ++i) {                         \
        const int f = w * 4 + i;                                              \
        NIDL[i] = ei[(f >> 3) * E_EDGES + g2 * 32 + (f & 7) * 4 + q];         \
      }                                                                       \
    }                                                                         \
    if (g < NG) {                                                             \
      const f32x4 at0 = *(const f32x4*)(attr + g * 32 + q * 4);               \
      const f32x4 at1 = *(const f32x4*)(attr + g * 32 + 16 + q * 4);          \
      _Pragma("unroll") for (int t = 0; t < 2; ++t) {                         \
        f32x4 a0 = {0.f, 0.f, 0.f, 0.f}, a1 = {0.f, 0.f, 0.f, 0.f};          \
        _Pragma("unroll") for (int s = 0; s < 8; ++s) {                       \
          const int ch = s * 4 + q;                                           \
          const s16x8 A = *(const s16x8*)&ef[P][(ch >> 4) * 8192 + t * 4096   \
              + l15 * 256 + (((ch & 15) ^ (l15 & 7)) << 4)];                  \
          a0 = __builtin_amdgcn_mfma_f32_16x16x32_bf16(A, B1[0][s], a0, 0, 0, 0); \
          a1 = __builtin_amdgcn_mfma_f32_16x16x32_bf16(A, B1[1][s], a1, 0, 0, 0); \
        }                                                                     \
        const f32x4 at = t ? at1 : at0;                                       \
        _Pragma("unroll") for (int r = 0; r < 4; ++r) {                       \
          const float v0 = fmaxf(a0[r] + b1v[0] + at[r] * w1l[0], 0.f);       \
          const float v1 = fmaxf(a1[r] + b1v[1] + at[r] * w1l[1], 0.f);       \
          const unsigned int pk =                                             \
              (unsigned)f2bf(v0) | ((unsigned)f2bf(v1) << 16);                \
          *(unsigned int*)&h1b[P][t * 4352 + (q * 4 + r) * 272                \
                                  + (w * 16 + l15) * 4] = pk;                 \
        }                                                                     \
      }                                                                       \
    }                                                                         \
    if (gm1 >= 0 && gm1 < NG) {                                               \
      const int t = w >> 1;                                                   \
      f32x4 c0 = {0.f, 0.f, 0.f, 0.f};                                        \
      _Pragma("unroll") for (int s2 = 0; s2 < 4; ++s2) {                      \
        const s16x8 A2 = *(const s16x8*)&h1b[(P) ^ 1][t * 4352 + l15 * 272    \
                                                      + s2 * 64 + q * 16];    \
        c0 = __builtin_amdgcn_mfma_f32_16x16x32_bf16(A2, B2[s2], c0, 0, 0, 0); \
      }                                                                       \
      float p0 = fmaxf(c0[0] + b2v, 0.f) * w3v;                               \
      float p1 = fmaxf(c0[1] + b2v, 0.f) * w3v;                               \
      float p2 = fmaxf(c0[2] + b2v, 0.f) * w3v;                               \
      float p3 = fmaxf(c0[3] + b2v, 0.f) * w3v;                               \
      _Pragma("unroll") for (int off = 8; off >= 1; off >>= 1) {              \
        p0 += __shfl_xor(p0, off, 16);                                        \
        p1 += __shfl_xor(p1, off, 16);                                        \
        p2 += __shfl_xor(p2, off, 16);                                        \
        p3 += __shfl_xor(p3, off, 16);                                        \
      }                                                                       \
      if (l15 == 0) {                                                         \
        red[P][w][q * 4 + 0] = p0;                                            \
        red[P][w][q * 4 + 1] = p1;                                            \
        red[P][w][q * 4 + 2] = p2;                                            \
        red[P][w][q * 4 + 3] = p3;                                            \
      }                                                                       \
    }                                                                         \
    if (gm2 >= 0 && tid < 32) {                                               \
      const int tt = tid >> 4, mm = tid & 15;                                 \
      const float sv = red[(P) ^ 1][tt * 2][mm]                               \
                     + red[(P) ^ 1][tt * 2 + 1][mm] + b3v;                    \
      out[gm2 * 32 + tid] = 1.f / (1.f + __expf(-sv));                        \
    }                                                                         \
    __syncthreads();                                                          \
  }

  for (int itb = 0;; itb += 2) {
    ITER(itb, 0, nidB, nidA)
    if (itb >= itmax) break;
    ITER(itb + 1, 1, nidA, nidB)
    if (itb + 1 >= itmax) break;
  }
#undef ITER
}

extern "C" void kernel_launch(void* const* d_in, const int* in_sizes, int n_in,
                              void* d_out, int out_size, void* d_ws, size_t ws_size,
                              hipStream_t stream) {
  const float* x    = (const float*)d_in[0];
  const int*   ei   = (const int*)d_in[1];
  const float* attr = (const float*)d_in[2];
  const float* W1   = (const float*)d_in[3];
  const float* b1   = (const float*)d_in[4];
  const float* W2   = (const float*)d_in[5];
  const float* b2   = (const float*)d_in[6];
  const float* W3   = (const float*)d_in[7];
  const float* b3   = (const float*)d_in[8];
  float* out = (float*)d_out;

  const size_t need = (size_t)NNODES * HID * sizeof(unsigned short);  // 25.6 MB
  if (ws_size >= need) {
    unsigned short* xb = (unsigned short*)d_ws;
    cast_x_kernel<<<6250, 256, 0, stream>>>(x, xb);
    edge_mlp_kernel<<<NBLK, 256, 0, stream>>>(xb, ei, attr, W1, b1, W2, b2, W3, b3, out);
  } else {
    edge_naive<<<(E_EDGES + 255) / 256, 256, 0, stream>>>(x, ei, attr, W1, b1, W2, b2, W3, b3, out);
  }
}